// Round 15
// baseline (416.453 us; speedup 1.0000x reference)
//
#include <hip/hip_runtime.h>

#define HIDDEN 128
#define NRBF 50
#define CUTOFF_F 5.0f
#define PI_OVER_CUTOFF 0.6283185307179586f
#define EPB 512          // edges per gather block (4 waves x 128)
#define BPITCH 36        // B LDS pitch (u32), 16B-aligned b128 reads
#define WPITCH 66        // W u32 pitch (per-wave region)
#define SLOT_U32 32      // 128B-aligned packed slot

typedef _Float16 half8_t __attribute__((ext_vector_type(8)));
using f32x4_t  = __attribute__((ext_vector_type(4))) float;
using short8_t = __attribute__((ext_vector_type(8))) short;
typedef __attribute__((ext_vector_type(2))) _Float16 hf2;

static __device__ __forceinline__ unsigned int pkh(float a, float b) {
    return __builtin_bit_cast(unsigned int, __builtin_amdgcn_cvt_pkrtz(a, b));
}
static __device__ __forceinline__ float cvlo(unsigned int u) {
    return (float)__builtin_bit_cast(hf2, u)[0];
}
static __device__ __forceinline__ float cvhi(unsigned int u) {
    return (float)__builtin_bit_cast(hf2, u)[1];
}
static __device__ __forceinline__ unsigned int pk_bf16(float a, float b) {
    unsigned int ua = __float_as_uint(a), ub = __float_as_uint(b);
    ua = (ua + 0x7FFFu + ((ua >> 16) & 1u)) >> 16;
    ub = (ub + 0x7FFFu + ((ub >> 16) & 1u)) >> 16;
    return ua | (ub << 16);
}

// ======================= CSR build =======================

__global__ __launch_bounds__(256) void hist_kernel(
    const int* __restrict__ ei, const float* __restrict__ ew,
    int* __restrict__ cnt, int E)
{
    int e = blockIdx.x * 256 + threadIdx.x;
    if (e >= E) return;
    float r = ew[e];
    if (r < CUTOFF_F) atomicAdd(&cnt[ei[e]], 1);
}

__global__ __launch_bounds__(256) void scan1_kernel(
    const int* __restrict__ cnt, int* __restrict__ rowptr,
    int* __restrict__ bsum, int N)
{
    __shared__ int sh[256];
    int t = threadIdx.x, b = blockIdx.x;
    int base = b * 1024 + t * 4;
    int v[4];
#pragma unroll
    for (int j = 0; j < 4; ++j) v[j] = (base + j < N) ? cnt[base + j] : 0;
    int s = v[0] + v[1] + v[2] + v[3];
    sh[t] = s;
    __syncthreads();
    for (int off = 1; off < 256; off <<= 1) {
        int x = (t >= off) ? sh[t - off] : 0;
        __syncthreads();
        sh[t] += x;
        __syncthreads();
    }
    int run = sh[t] - s;
#pragma unroll
    for (int j = 0; j < 4; ++j) {
        if (base + j < N) rowptr[base + j] = run;
        run += v[j];
    }
    if (t == 255) bsum[b] = sh[255];
}

__global__ __launch_bounds__(256) void scan2_kernel(
    int* __restrict__ bsum, int* __restrict__ rowptr, int nb, int N)
{
    __shared__ int sh[256];
    int t = threadIdx.x;
    int v = (t < nb) ? bsum[t] : 0;
    sh[t] = v;
    __syncthreads();
    for (int off = 1; off < 256; off <<= 1) {
        int x = (t >= off) ? sh[t - off] : 0;
        __syncthreads();
        sh[t] += x;
        __syncthreads();
    }
    if (t < nb) bsum[t] = sh[t] - v;
    if (t == 255) rowptr[N] = sh[255];
}

__global__ __launch_bounds__(256) void scan3_kernel(
    int* __restrict__ rowptr, int* __restrict__ woff,
    const int* __restrict__ bsum, int N)
{
    int t = threadIdx.x, b = blockIdx.x;
    int base = b * 1024 + t * 4;
    int off = bsum[b];
#pragma unroll
    for (int j = 0; j < 4; ++j) {
        int i = base + j;
        if (i < N) {
            int r = rowptr[i] + off;
            rowptr[i] = r;
            woff[i] = r;
        }
    }
}

// pad slots/desc beyond M with zeros + build packed emb (fused utility)
__global__ __launch_bounds__(256) void pad_pack_kernel(
    const int* __restrict__ rowptr, int N,
    int* __restrict__ desc, unsigned int* __restrict__ slots,
    const float* __restrict__ emb, unsigned int* __restrict__ embp, int NT)
{
    int M = rowptr[N];
    int t = blockIdx.x * 256 + threadIdx.x;
    if (t < 512) desc[M + t] = 0;
    size_t sb = (size_t)M * SLOT_U32;
    for (int i = t; i < 512 * SLOT_U32; i += 256 * gridDim.x)
        slots[sb + i] = 0u;
    if (t < NT * 64) {
        int r = t >> 6, j = t & 63;
        embp[t] = pkh(emb[r * HIDDEN + j], emb[r * HIDDEN + j + 64]);
    }
}

// ======================= tier-1 scatter+pack =======================
// Per 128-edge block: stage ea via coalesced float4 -> LDS; compute C; write
// desc + a 128B-aligned f16 slot [C*ea | C | 0] at the CSR position.
// Slot = exactly 2 full 64B lines written by one thread (no RMW).
__global__ __launch_bounds__(256) void scatter_pack2(
    const int* __restrict__ z, const int* __restrict__ ei,
    const float* __restrict__ ew, const float* __restrict__ ea,
    int* __restrict__ woff, int* __restrict__ desc,
    unsigned int* __restrict__ slots, int E)
{
    __shared__ float ls[128 * NRBF];     // 25.6KB
    __shared__ int   lp[128];
    __shared__ float lc[128];
    int tid  = threadIdx.x;
    int base = blockIdx.x * 128;
    int cnt  = min(128, E - base);
    if (cnt <= 0) return;

    // stage ea coalesced (contiguous float4 stream)
    const float* src = ea + (size_t)base * NRBF;
    int nf4 = (cnt * NRBF) >> 2;
    for (int i = tid; i < nf4; i += 256)
        *(float4*)&ls[i * 4] = *(const float4*)&src[i * 4];
    for (int i = nf4 * 4 + tid; i < cnt * NRBF; i += 256)
        ls[i] = src[i];

    if (tid < cnt) {
        int e = base + tid;
        float r = ew[e];
        int p = -1; float C = 0.f;
        if (r < CUTOFF_F) {
            C = 0.5f * (cosf(r * PI_OVER_CUTOFF) + 1.0f);
            int s = ei[e], d = ei[E + e];
            p = atomicAdd(&woff[s], 1);
            desc[p] = s | (z[d] << 20);
        }
        lp[tid] = p; lc[tid] = C;
    }
    __syncthreads();

    int e = tid >> 1, h = tid & 1;
    if (e >= cnt) return;
    int p = lp[e];
    if (p < 0) return;
    float C = lc[e];
    const float* row = &ls[e * NRBF];
    unsigned int buf[16];
    if (h == 0) {
#pragma unroll
        for (int q = 0; q < 16; ++q)
            buf[q] = pkh(C * row[2 * q], C * row[2 * q + 1]);
    } else {
#pragma unroll
        for (int q = 0; q < 9; ++q)
            buf[q] = pkh(C * row[32 + 2 * q], C * row[33 + 2 * q]);
        buf[9] = pkh(C, 0.f);            // k=50 constant column
#pragma unroll
        for (int q = 10; q < 16; ++q) buf[q] = 0u;
    }
    uint4* dst = (uint4*)(slots + (size_t)p * SLOT_U32 + h * 16);
#pragma unroll
    for (int q = 0; q < 4; ++q) dst[q] = ((const uint4*)buf)[q];
}

// ======================= tier-1 gather: sequential-slot MFMA =======================
// Slots are CSR-contiguous -> A fragments stream sequentially. R13 pipelining
// for desc (per-lane vectors + readlane) and emb (1-tile-early).
__global__ __launch_bounds__(256) void gather_mfma2(
    const int* __restrict__ rowptr, const int* __restrict__ desc,
    const unsigned int* __restrict__ slots, const unsigned int* __restrict__ embp,
    const float* __restrict__ dpw, const float* __restrict__ dpb,
    float* __restrict__ agg, int N)
{
    __shared__ unsigned int Blds[128 * BPITCH];   // 18432B
    __shared__ unsigned int Wsh[4][16 * WPITCH];  // 16896B
    int M = rowptr[N];

    // bijective XCD-chunk swizzle
    int nwg = gridDim.x, orig = blockIdx.x;
    int q = nwg >> 3, r8 = nwg & 7, xcd = orig & 7, sub = orig >> 3;
    int lb = (xcd < r8) ? xcd * (q + 1) + sub
                        : r8 * (q + 1) + (xcd - r8) * q + sub;
    int gbase = lb * EPB;
    if (gbase >= M) return;

    int tid  = threadIdx.x;
    int w    = tid >> 6;
    int lane = tid & 63;
    int cc   = lane & 15;
    int g    = lane >> 4;
    int l16  = lane & 15;

    // stage B (f16 k-pairs, pitch 36)
    for (int idx = tid; idx < 128 * 32; idx += 256) {
        int h = idx >> 5, p = idx & 31;
        unsigned int u = 0u;
        if (p < 25) {
            float2 v = *(const float2*)(dpw + h * NRBF + 2 * p);
            u = pkh(v.x, v.y);
        } else if (p == 25) {
            u = pkh(dpb[h], 0.f);
        }
        Blds[h * BPITCH + p] = u;
    }
    __syncthreads();

    unsigned int* Ww = Wsh[w];
    int wbeg = gbase + w * 128;
    if (wbeg >= M) return;

    bool runc;
    if (wbeg == 0) runc = true;
    else runc = ((desc[wbeg - 1] & 0xFFFFF) != (desc[wbeg] & 0xFFFFF));

    const int* descb = desc + wbeg;

#define XTR16(V, S)                                                            \
    _Pragma("unroll")                                                          \
    for (int j_ = 0; j_ < 16; ++j_) S[j_] = __builtin_amdgcn_readlane((V), j_);

    int sd0[16], sd1[16], sdN[16];
    unsigned int evpC[16];
    uint4 A0c, A1c;

    // ---- prologue ----
    {
        int dv0 = descb[0 * 16 + l16];
        int dv1 = descb[1 * 16 + l16];
        XTR16(dv0, sd0);
        XTR16(dv1, sd1);
    }
    int dq0 = descb[2 * 16 + l16], dq1 = descb[3 * 16 + l16];
    {
        const uint4* sp0 = (const uint4*)(slots + (size_t)(wbeg + cc) * SLOT_U32);
        A0c = sp0[g];
        A1c = (g < 3) ? sp0[4 + g] : make_uint4(0u, 0u, 0u, 0u);
    }
#pragma unroll
    for (int j = 0; j < 16; ++j)
        evpC[j] = embp[(((unsigned int)sd0[j]) >> 20) * 64 + lane];

    int   cur = -1;
    float r0 = 0.f, r1 = 0.f;

    for (int t = 0; t < 8; ++t) {
        uint4 A0u = A0c, A1u = A1c;
        // prefetch next tile's A (sequential; pad keeps it valid)
        {
            const uint4* spn = (const uint4*)(slots + (size_t)(wbeg + (t + 1) * 16 + cc) * SLOT_U32);
            A0c = spn[g];
            A1c = (g < 3) ? spn[4 + g] : make_uint4(0u, 0u, 0u, 0u);
        }
        // rotate desc queue: extract t+2, issue t+4
        XTR16(dq0, sdN);
        dq0 = dq1;
        dq1 = descb[(t + 4) * 16 + l16];

        // MFMA
        half8_t A0 = __builtin_bit_cast(half8_t, A0u);
        half8_t A1 = __builtin_bit_cast(half8_t, A1u);
        f32x4_t acc[8];
#pragma unroll
        for (int nt = 0; nt < 8; ++nt) {
            uint4 b0 = *(const uint4*)&Blds[(nt * 16 + cc) * BPITCH + 4 * g];
            uint4 b1 = *(const uint4*)&Blds[(nt * 16 + cc) * BPITCH + 16 + 4 * g];
            f32x4_t a = (f32x4_t){0.f, 0.f, 0.f, 0.f};
            a = __builtin_amdgcn_mfma_f32_16x16x32_f16(A0, __builtin_bit_cast(half8_t, b0), a, 0, 0, 0);
            a = __builtin_amdgcn_mfma_f32_16x16x32_f16(A1, __builtin_bit_cast(half8_t, b1), a, 0, 0, 0);
            acc[nt] = a;
        }
        // W transpose (f16 pairs h, h+64)
#pragma unroll
        for (int m = 0; m < 4; ++m)
#pragma unroll
            for (int r = 0; r < 4; ++r)
                Ww[(g * 4 + r) * WPITCH + m * 16 + cc] = pkh(acc[m][r], acc[m + 4][r]);
        unsigned int wv[16];
#pragma unroll
        for (int e2 = 0; e2 < 16; ++e2)
            wv[e2] = Ww[e2 * WPITCH + lane];

        // register run-merge
#pragma unroll
        for (int e2 = 0; e2 < 16; ++e2) {
            int src_ = sd0[e2] & 0xFFFFF;
            if (src_ != cur) {
                if (cur >= 0) {
                    float* dst_ = agg + (size_t)cur * HIDDEN + lane;
                    if (runc) { dst_[0] = r0; dst_[64] = r1; }
                    else { unsafeAtomicAdd(dst_, r0); unsafeAtomicAdd(dst_ + 64, r1); }
                    runc = true;
                }
                cur = src_; r0 = 0.f; r1 = 0.f;
            }
            r0 = fmaf(cvlo(wv[e2]), cvlo(evpC[e2]), r0);
            r1 = fmaf(cvhi(wv[e2]), cvhi(evpC[e2]), r1);
        }
        // evp for tile t+1
#pragma unroll
        for (int j = 0; j < 16; ++j)
            evpC[j] = embp[(((unsigned int)sd1[j]) >> 20) * 64 + lane];
        // rotate descriptor scalars
#pragma unroll
        for (int j = 0; j < 16; ++j) { sd0[j] = sd1[j]; sd1[j] = sdN[j]; }
    }
#undef XTR16

    // final flush
    if (cur >= 0) {
        int nxt = desc[wbeg + 128] & 0xFFFFF;
        float* dst = agg + (size_t)cur * HIDDEN + lane;
        if (runc && nxt != cur) {
            dst[0]  = r0;
            dst[64] = r1;
        } else {
            unsafeAtomicAdd(dst,      r0);
            unsafeAtomicAdd(dst + 64, r1);
        }
    }
}

// ======================= tier-2 scatter/gather (fallback) =======================
__global__ __launch_bounds__(256) void scatter_slim(
    const int* __restrict__ z, const int* __restrict__ ei,
    const float* __restrict__ ew, int* __restrict__ woff,
    int* __restrict__ desc, int* __restrict__ eidA, float* __restrict__ CA,
    int E)
{
    int e = blockIdx.x * 256 + threadIdx.x;
    if (e >= E) return;
    float r = ew[e];
    if (!(r < CUTOFF_F)) return;
    float C = 0.5f * (cosf(r * PI_OVER_CUTOFF) + 1.0f);
    int src = ei[e];
    int dst = ei[E + e];
    int zt  = z[dst];
    int p = atomicAdd(&woff[src], 1);
    desc[p] = src | (zt << 20);
    eidA[p] = e;
    CA[p]   = C;
}

__global__ __launch_bounds__(256) void gather_stream(
    const int* __restrict__ rowptr, const int* __restrict__ desc,
    const float* __restrict__ cC, const int* __restrict__ eidA,
    const float* __restrict__ ea, const float* __restrict__ emb,
    const float* __restrict__ dpw, const float* __restrict__ dpb,
    float* __restrict__ agg, int N, int nwaves)
{
    __shared__ unsigned int sh_ea[4][4][32];
    int lane  = threadIdx.x & 63;
    int wslot = threadIdx.x >> 6;
    int wid = __builtin_amdgcn_readfirstlane((int)((blockIdx.x * blockDim.x + threadIdx.x) >> 6));

    hf2 whA[25], whB[25];
    {
        const float* wr0 = dpw + (size_t)(2 * lane) * NRBF;
        const float* wr1 = wr0 + NRBF;
#pragma unroll
        for (int q = 0; q < 25; ++q) {
            float2 x = *(const float2*)(wr0 + 2 * q);
            float2 y = *(const float2*)(wr1 + 2 * q);
            whA[q] = __builtin_bit_cast(hf2, pkh(x.x, x.y));
            whB[q] = __builtin_bit_cast(hf2, pkh(y.x, y.y));
        }
    }
    float2 db = *(const float2*)(dpb + 2 * lane);

    int M  = rowptr[N];
    int CH = (M + nwaves - 1) / nwaves;
    int c0 = min(wid * CH, M);
    int c1 = min(c0 + CH, M);

    int   cur = -1, run_start = c0;
    float a0 = 0.f, a1 = 0.f;

    for (int i = c0; i < c1; i += 4) {
        int sv[4]; float cf[4]; int ed[4]; float2 ev[4]; float2 eaf[4];
#pragma unroll
        for (int j = 0; j < 4; ++j)
            if (i + j < c1) { sv[j] = desc[i + j]; cf[j] = cC[i + j]; ed[j] = eidA[i + j]; }
#pragma unroll
        for (int j = 0; j < 4; ++j)
            if (i + j < c1) ev[j] = *(const float2*)(emb + (size_t)((unsigned int)sv[j] >> 20) * HIDDEN + 2 * lane);
#pragma unroll
        for (int j = 0; j < 4; ++j)
            if (i + j < c1 && lane < 25) eaf[j] = *(const float2*)(ea + (size_t)ed[j] * NRBF + 2 * lane);
#pragma unroll
        for (int j = 0; j < 4; ++j)
            if (i + j < c1 && lane < 28) {
                unsigned int u = 0u;
                if (lane < 25) u = pkh(eaf[j].x, eaf[j].y);
                sh_ea[wslot][j][lane] = u;
            }
#pragma unroll
        for (int j = 0; j < 4; ++j) {
            if (i + j >= c1) break;
            int src = sv[j] & 0xFFFFF;
            if (src != cur) {
                if (cur >= 0) {
                    int rp0 = rowptr[cur], rp1 = rowptr[cur + 1];
                    float* dst = agg + (size_t)cur * HIDDEN + 2 * lane;
                    if (run_start == rp0 && (i + j) == rp1) {
                        *(float2*)dst = make_float2(a0, a1);
                    } else {
                        unsafeAtomicAdd(dst, a0);
                        unsafeAtomicAdd(dst + 1, a1);
                    }
                }
                cur = src; run_start = i + j; a0 = 0.f; a1 = 0.f;
            }
            float s0 = 0.f, s1 = 0.f;
#pragma unroll
            for (int qq = 0; qq < 6; ++qq) {
                uint4 u = *(const uint4*)&sh_ea[wslot][j][qq * 4];
#pragma unroll
                for (int t = 0; t < 4; ++t) {
                    unsigned int ww = (t == 0) ? u.x : (t == 1) ? u.y : (t == 2) ? u.z : u.w;
                    hf2 e2 = __builtin_bit_cast(hf2, ww);
                    s0 = fmaf((float)e2[0], (float)whA[qq*4+t][0], fmaf((float)e2[1], (float)whA[qq*4+t][1], s0));
                    s1 = fmaf((float)e2[0], (float)whB[qq*4+t][0], fmaf((float)e2[1], (float)whB[qq*4+t][1], s1));
                }
            }
            {
                hf2 e2 = __builtin_bit_cast(hf2, sh_ea[wslot][j][24]);
                s0 = fmaf((float)e2[0], (float)whA[24][0], fmaf((float)e2[1], (float)whA[24][1], s0));
                s1 = fmaf((float)e2[0], (float)whB[24][0], fmaf((float)e2[1], (float)whB[24][1], s1));
            }
            float W0 = (s0 + db.x) * cf[j];
            float W1 = (s1 + db.y) * cf[j];
            a0 = fmaf(W0, ev[j].x, a0);
            a1 = fmaf(W1, ev[j].y, a1);
        }
    }
    if (cur >= 0) {
        int rp0 = rowptr[cur], rp1 = rowptr[cur + 1];
        float* dst = agg + (size_t)cur * HIDDEN + 2 * lane;
        if (run_start == rp0 && c1 == rp1) {
            *(float2*)dst = make_float2(a0, a1);
        } else {
            unsafeAtomicAdd(dst, a0);
            unsafeAtomicAdd(dst + 1, a1);
        }
    }
}

// ======================= tier-3 fallback =======================
__global__ __launch_bounds__(256) void edge_kernel(
    const int* __restrict__ z, const int* __restrict__ ei,
    const float* __restrict__ ew, const float* __restrict__ ea,
    const float* __restrict__ emb, const float* __restrict__ dpw,
    const float* __restrict__ dpb, float* __restrict__ agg, int E)
{
    int e = blockIdx.x * 256 + threadIdx.x;
    if (e >= E) return;
    float r = ew[e];
    if (!(r < CUTOFF_F)) return;
    float C = 0.5f * (cosf(r * PI_OVER_CUTOFF) + 1.0f);
    int src = ei[e];
    int dst = ei[E + e];
    int zt  = z[dst];
    float av[NRBF];
#pragma unroll
    for (int k = 0; k < NRBF; ++k) av[k] = ea[(size_t)e * NRBF + k];
    const float* er = emb + (size_t)zt * HIDDEN;
    float*       ar = agg + (size_t)src * HIDDEN;
#pragma unroll 2
    for (int h = 0; h < HIDDEN; ++h) {
        const float* wrow = dpw + h * NRBF;
        float s0 = 0.f, s1 = 0.f;
#pragma unroll
        for (int k = 0; k < NRBF; k += 2) {
            s0 = fmaf(av[k],     wrow[k],     s0);
            s1 = fmaf(av[k + 1], wrow[k + 1], s1);
        }
        float w2 = (dpb[h] + s0 + s1) * C;
        unsafeAtomicAdd(&ar[h], w2 * er[h]);
    }
}

// ======================= Combine: bf16 MFMA GEMM =======================
__global__ __launch_bounds__(256) void combine_mfma(
    const float* __restrict__ nf, const float* __restrict__ cw,
    const float* __restrict__ cbias, float* out, int N)
{
    __shared__ unsigned int As_u[64 * 20];
    __shared__ unsigned int Bs_u[128 * 20];
    int tid  = threadIdx.x;
    int w    = tid >> 6;
    int lane = tid & 63;
    int c    = lane & 15;
    int g    = lane >> 4;
    int row0 = blockIdx.x * 64;

    f32x4_t acc[8];
#pragma unroll
    for (int q = 0; q < 8; ++q) acc[q] = (f32x4_t){0.f, 0.f, 0.f, 0.f};

    for (int ks = 0; ks < 8; ++ks) {
        const float* src = (ks < 4) ? nf : out;
        int kb = (ks & 3) * 32;
        {
            int r = tid >> 2, kq = tid & 3;
            int row = row0 + r;
            float4 v0 = make_float4(0.f, 0.f, 0.f, 0.f), v1 = v0;
            if (row < N) {
                const float4* p = (const float4*)(src + (size_t)row * HIDDEN + kb + kq * 8);
                v0 = p[0]; v1 = p[1];
            }
            *(uint4*)&As_u[r * 20 + kq * 4] =
                make_uint4(pk_bf16(v0.x, v0.y), pk_bf16(v0.z, v0.w),
                           pk_bf16(v1.x, v1.y), pk_bf16(v1.z, v1.w));
        }
        {
            int j = tid >> 1, hf = tid & 1;
            const float4* p = (const float4*)(cw + (size_t)j * 256 + ks * 32 + hf * 16);
            float4 b0 = p[0], b1 = p[1], b2 = p[2], b3 = p[3];
            *(uint4*)&Bs_u[j * 20 + hf * 8] =
                make_uint4(pk_bf16(b0.x, b0.y), pk_bf16(b0.z, b0.w),
                           pk_bf16(b1.x, b1.y), pk_bf16(b1.z, b1.w));
            *(uint4*)&Bs_u[j * 20 + hf * 8 + 4] =
                make_uint4(pk_bf16(b2.x, b2.y), pk_bf16(b2.z, b2.w),
                           pk_bf16(b3.x, b3.y), pk_bf16(b3.z, b3.w));
        }
        __syncthreads();
        uint4 au = *(const uint4*)&As_u[(w * 16 + c) * 20 + g * 4];
        short8_t af = __builtin_bit_cast(short8_t, au);
#pragma unroll
        for (int cbk = 0; cbk < 8; ++cbk) {
            uint4 bu = *(const uint4*)&Bs_u[(cbk * 16 + c) * 20 + g * 4];
            short8_t bf = __builtin_bit_cast(short8_t, bu);
            acc[cbk] = __builtin_amdgcn_mfma_f32_16x16x32_bf16(af, bf, acc[cbk], 0, 0, 0);
        }
        __syncthreads();
    }
#pragma unroll
    for (int cbk = 0; cbk < 8; ++cbk) {
        float bias = cbias[cbk * 16 + c];
#pragma unroll
        for (int r = 0; r < 4; ++r) {
            int row = row0 + w * 16 + g * 4 + r;
            if (row < N) out[(size_t)row * HIDDEN + cbk * 16 + c] = acc[cbk][r] + bias;
        }
    }
}

// ======================= launch =======================

extern "C" void kernel_launch(void* const* d_in, const int* in_sizes, int n_in,
                              void* d_out, int out_size, void* d_ws, size_t ws_size,
                              hipStream_t stream)
{
    const int*   z   = (const int*)  d_in[0];
    const float* nf  = (const float*)d_in[1];
    const int*   ei  = (const int*)  d_in[2];
    const float* ew  = (const float*)d_in[3];
    const float* ea  = (const float*)d_in[4];
    const float* emb = (const float*)d_in[5];
    const float* dpw = (const float*)d_in[6];
    const float* dpb = (const float*)d_in[7];
    const float* cw  = (const float*)d_in[8];
    const float* cb  = (const float*)d_in[9];
    float* out = (float*)d_out;

    int N = in_sizes[0];
    int E = in_sizes[3];
    int NT = in_sizes[5] / HIDDEN;   // emb rows (95)

    size_t hdr  = ((size_t)2 * N + 1 + 1024 + 3) & ~(size_t)3;   // u32s
    size_t Epad = (size_t)E + 512;
    size_t need1 = (hdr + Epad * (1 + SLOT_U32) + (size_t)NT * 64 + 16) * 4;
    size_t need2 = (hdr + (size_t)3 * E) * 4;

    (void)hipMemsetAsync(out, 0, (size_t)N * HIDDEN * sizeof(float), stream);

    int nb1 = (N + 1023) / 1024;

    if (ws_size >= need1) {
        int* rowptr = (int*)d_ws;
        int* woff   = rowptr + (N + 1);
        int* bsum   = woff + N;
        int* desc   = (int*)d_ws + hdr;
        unsigned int* slots = (unsigned int*)(desc + Epad);
        unsigned int* embp  = slots + Epad * SLOT_U32;

        (void)hipMemsetAsync(woff, 0, (size_t)N * 4, stream);
        hist_kernel<<<(E + 255) / 256, 256, 0, stream>>>(ei, ew, woff, E);
        scan1_kernel<<<nb1, 256, 0, stream>>>(woff, rowptr, bsum, N);
        scan2_kernel<<<1, 256, 0, stream>>>(bsum, rowptr, nb1, N);
        scan3_kernel<<<nb1, 256, 0, stream>>>(rowptr, woff, bsum, N);
        pad_pack_kernel<<<64, 256, 0, stream>>>(rowptr, N, desc, slots,
                                                emb, embp, NT);
        scatter_pack2<<<(E + 127) / 128, 256, 0, stream>>>(z, ei, ew, ea,
                                                           woff, desc, slots, E);
        int nblk = (E + EPB - 1) / EPB;
        gather_mfma2<<<nblk, 256, 0, stream>>>(rowptr, desc, slots, embp,
                                               dpw, dpb, out, N);
    } else if (ws_size >= need2) {
        int* rowptr = (int*)d_ws;
        int* woff   = rowptr + (N + 1);
        int* bsum   = woff + N;
        int* desc   = (int*)d_ws + hdr;
        float* cCA  = (float*)(desc + E);
        int* eidA   = (int*)(cCA + E);

        (void)hipMemsetAsync(woff, 0, (size_t)N * 4, stream);
        hist_kernel<<<(E + 255) / 256, 256, 0, stream>>>(ei, ew, woff, E);
        scan1_kernel<<<nb1, 256, 0, stream>>>(woff, rowptr, bsum, N);
        scan2_kernel<<<1, 256, 0, stream>>>(bsum, rowptr, nb1, N);
        scan3_kernel<<<nb1, 256, 0, stream>>>(rowptr, woff, bsum, N);
        scatter_slim<<<(E + 255) / 256, 256, 0, stream>>>(z, ei, ew, woff,
                                                          desc, eidA, cCA, E);
        const int blocks = 2048;
        gather_stream<<<blocks, 256, 0, stream>>>(rowptr, desc, cCA, eidA,
                                                  ea, emb, dpw, dpb, out, N,
                                                  blocks * 4);
    } else {
        edge_kernel<<<(E + 255) / 256, 256, 0, stream>>>(z, ei, ew, ea, emb,
                                                         dpw, dpb, out, E);
    }

    combine_mfma<<<(N + 63) / 64, 256, 0, stream>>>(nf, cw, cb, out, N);
}

// Round 16
// 362.986 us; speedup vs baseline: 1.1473x; 1.1473x over previous
//
#include <hip/hip_runtime.h>

#define HIDDEN 128
#define NRBF 50
#define CUTOFF_F 5.0f
#define PI_OVER_CUTOFF 0.6283185307179586f
#define EPB 512          // edges per block in gather (4 waves x 128)
#define BPITCH 36        // B LDS pitch (u32), 16B-aligned b128 reads
#define ASTP 68          // Ast f32 pitch (per-wave region, aliased by W)
#define WPITCH 66        // W u32 pitch inside the same region

typedef _Float16 half8_t __attribute__((ext_vector_type(8)));
using f32x4_t  = __attribute__((ext_vector_type(4))) float;
using short8_t = __attribute__((ext_vector_type(8))) short;
typedef __attribute__((ext_vector_type(2))) _Float16 hf2;

static __device__ __forceinline__ unsigned int pkh(float a, float b) {
    return __builtin_bit_cast(unsigned int, __builtin_amdgcn_cvt_pkrtz(a, b));
}
static __device__ __forceinline__ float cvlo(unsigned int u) {
    return (float)__builtin_bit_cast(hf2, u)[0];
}
static __device__ __forceinline__ float cvhi(unsigned int u) {
    return (float)__builtin_bit_cast(hf2, u)[1];
}
static __device__ __forceinline__ unsigned int pk_bf16(float a, float b) {
    unsigned int ua = __float_as_uint(a), ub = __float_as_uint(b);
    ua = (ua + 0x7FFFu + ((ua >> 16) & 1u)) >> 16;
    ub = (ub + 0x7FFFu + ((ub >> 16) & 1u)) >> 16;
    return ua | (ub << 16);
}

// ======================= CSR build =======================

__global__ __launch_bounds__(256) void hist_kernel(
    const int* __restrict__ ei, const float* __restrict__ ew,
    int* __restrict__ cnt, int E)
{
    int e = blockIdx.x * 256 + threadIdx.x;
    if (e >= E) return;
    float r = ew[e];
    if (r < CUTOFF_F) atomicAdd(&cnt[ei[e]], 1);
}

__global__ __launch_bounds__(256) void scan1_kernel(
    const int* __restrict__ cnt, int* __restrict__ rowptr,
    int* __restrict__ bsum, int N)
{
    __shared__ int sh[256];
    int t = threadIdx.x, b = blockIdx.x;
    int base = b * 1024 + t * 4;
    int v[4];
#pragma unroll
    for (int j = 0; j < 4; ++j) v[j] = (base + j < N) ? cnt[base + j] : 0;
    int s = v[0] + v[1] + v[2] + v[3];
    sh[t] = s;
    __syncthreads();
    for (int off = 1; off < 256; off <<= 1) {
        int x = (t >= off) ? sh[t - off] : 0;
        __syncthreads();
        sh[t] += x;
        __syncthreads();
    }
    int run = sh[t] - s;
#pragma unroll
    for (int j = 0; j < 4; ++j) {
        if (base + j < N) rowptr[base + j] = run;
        run += v[j];
    }
    if (t == 255) bsum[b] = sh[255];
}

__global__ __launch_bounds__(256) void scan2_kernel(
    int* __restrict__ bsum, int* __restrict__ rowptr, int nb, int N)
{
    __shared__ int sh[256];
    int t = threadIdx.x;
    int v = (t < nb) ? bsum[t] : 0;
    sh[t] = v;
    __syncthreads();
    for (int off = 1; off < 256; off <<= 1) {
        int x = (t >= off) ? sh[t - off] : 0;
        __syncthreads();
        sh[t] += x;
        __syncthreads();
    }
    if (t < nb) bsum[t] = sh[t] - v;
    if (t == 255) rowptr[N] = sh[255];
}

__global__ __launch_bounds__(256) void scan3_kernel(
    int* __restrict__ rowptr, int* __restrict__ woff,
    const int* __restrict__ bsum, int N)
{
    int t = threadIdx.x, b = blockIdx.x;
    int base = b * 1024 + t * 4;
    int off = bsum[b];
#pragma unroll
    for (int j = 0; j < 4; ++j) {
        int i = base + j;
        if (i < N) {
            int r = rowptr[i] + off;
            rowptr[i] = r;
            woff[i] = r;
        }
    }
}

// fused: zero pad region [M, M+512) of desc/eid/C + build packed emb
__global__ __launch_bounds__(256) void pad_pack_kernel(
    const int* __restrict__ rowptr, int N,
    int* __restrict__ desc, int* __restrict__ eidA, float* __restrict__ CA,
    const float* __restrict__ emb, unsigned int* __restrict__ embp, int NT)
{
    int M = rowptr[N];
    int t = blockIdx.x * 256 + threadIdx.x;
    if (t < 512) { desc[M + t] = 0; eidA[M + t] = 0; CA[M + t] = 0.f; }
    if (t < NT * 64) {
        int r = t >> 6, j = t & 63;
        embp[t] = pkh(emb[r * HIDDEN + j], emb[r * HIDDEN + j + 64]);
    }
}

// tier-1 scatter: slim descriptors only (12B/edge, L2-absorbed)
__global__ __launch_bounds__(256) void scatter_slim(
    const int* __restrict__ z, const int* __restrict__ ei,
    const float* __restrict__ ew, int* __restrict__ woff,
    int* __restrict__ desc, int* __restrict__ eidA, float* __restrict__ CA,
    int E)
{
    int e = blockIdx.x * 256 + threadIdx.x;
    if (e >= E) return;
    float r = ew[e];
    if (!(r < CUTOFF_F)) return;
    float C = 0.5f * (cosf(r * PI_OVER_CUTOFF) + 1.0f);
    int src = ei[e];
    int dst = ei[E + e];
    int zt  = z[dst];
    int p = atomicAdd(&woff[src], 1);
    desc[p] = src | (zt << 20);
    eidA[p] = e;
    CA[p]   = C;
}

// ======================= tier-1 gather: direct-ea streaming MFMA =======================
// R12 structure; desc/eid streams loaded as coalesced per-lane vectors queued
// 2 tiles deep, extracted with v_readlane; evp (emb) issued one tile early.
// (Best-measured configuration: 369.6us total, gather ~184.5us.)
__global__ __launch_bounds__(256) void gather_mfma(
    const int* __restrict__ rowptr, const int* __restrict__ desc,
    const int* __restrict__ eidA, const float* __restrict__ CA,
    const float* __restrict__ ea, const unsigned int* __restrict__ embp,
    const float* __restrict__ dpw, const float* __restrict__ dpb,
    float* __restrict__ agg, int N)
{
    __shared__ unsigned int Blds[128 * BPITCH];   // 18432B
    __shared__ float Rsh_all[4][16 * ASTP];       // 17408B (Ast f32 / W u32)
    int M = rowptr[N];

    // bijective XCD-chunk swizzle
    int nwg = gridDim.x, orig = blockIdx.x;
    int q = nwg >> 3, r8 = nwg & 7, xcd = orig & 7, sub = orig >> 3;
    int lb = (xcd < r8) ? xcd * (q + 1) + sub
                        : r8 * (q + 1) + (xcd - r8) * q + sub;
    int gbase = lb * EPB;
    if (gbase >= M) return;

    int tid  = threadIdx.x;
    int w    = tid >> 6;
    int lane = tid & 63;
    int cc   = lane & 15;
    int g    = lane >> 4;
    int lidx = min(lane, 49);
    int l16  = lane & 15;

    // stage B (f16 k-pairs, pitch 36): p<25 dpw, p==25 (dpb,0), rest zero
    for (int idx = tid; idx < 128 * 32; idx += 256) {
        int h = idx >> 5, p = idx & 31;
        unsigned int u = 0u;
        if (p < 25) {
            float2 v = *(const float2*)(dpw + h * NRBF + 2 * p);
            u = pkh(v.x, v.y);
        } else if (p == 25) {
            u = pkh(dpb[h], 0.f);
        }
        Blds[h * BPITCH + p] = u;
    }
    __syncthreads();

    float*        AstW = Rsh_all[w];
    unsigned int* Ww   = (unsigned int*)AstW;
    int wbeg = gbase + w * 128;
    if (wbeg >= M) return;

    bool runc;
    if (wbeg == 0) runc = true;
    else runc = ((desc[wbeg - 1] & 0xFFFFF) != (desc[wbeg] & 0xFFFFF));

    const int* descb = desc + wbeg;
    const int* eidb  = eidA + wbeg;

#define XTR16(V, S)                                                            \
    _Pragma("unroll")                                                          \
    for (int j_ = 0; j_ < 16; ++j_) S[j_] = __builtin_amdgcn_readlane((V), j_);

    int sd0[16], sd1[16], sdN[16], sp[16];
    float vrA[16], vrB[16];
    float vCA_, vCB_;
    unsigned int evpC[16];

    // ---- prologue ----
    {
        int dv0 = descb[0 * 16 + l16];
        int dv1 = descb[1 * 16 + l16];
        int ev0 = eidb [0 * 16 + l16];
        int ev1 = eidb [1 * 16 + l16];
        XTR16(dv0, sd0);
        XTR16(dv1, sd1);
        int se[16];
        XTR16(ev0, se);
#pragma unroll
        for (int j = 0; j < 16; ++j)
            vrA[j] = ea[(size_t)(unsigned int)se[j] * NRBF + lidx];
        XTR16(ev1, se);
#pragma unroll
        for (int j = 0; j < 16; ++j)
            vrB[j] = ea[(size_t)(unsigned int)se[j] * NRBF + lidx];
    }
    // in-flight queues for tiles 2,3
    int dq0 = descb[2 * 16 + l16], dq1 = descb[3 * 16 + l16];
    int eq0 = eidb [2 * 16 + l16], eq1 = eidb [3 * 16 + l16];
    vCA_ = CA[wbeg + cc];
    vCB_ = CA[wbeg + 16 + cc];
    // evp for tile 0
#pragma unroll
    for (int j = 0; j < 16; ++j)
        evpC[j] = embp[(((unsigned int)sd0[j]) >> 20) * 64 + lane];

    int   cur = -1;
    float r0 = 0.f, r1 = 0.f;

#define GBODY(VRC, VCC, T)                                                     \
{                                                                              \
    const int t_ = (T);                                                        \
    float vC = VCC;                                                            \
    /* extract eids(t+2) (loaded 2 tiles ago - no wait stall) */               \
    XTR16(eq0, sp);                                                            \
    /* stage Ast f32 (register -> LDS) */                                      \
    _Pragma("unroll")                                                          \
    for (int j = 0; j < 16; ++j)                                               \
        AstW[j * ASTP + lane] = VRC[j];                                        \
    /* reissue ea buffer for tile t+2 */                                       \
    _Pragma("unroll")                                                          \
    for (int j = 0; j < 16; ++j)                                               \
        VRC[j] = ea[(size_t)(unsigned int)sp[j] * NRBF + lidx];                \
    VCC = CA[wbeg + (t_ + 2) * 16 + cc];                                       \
    /* rotate queues; issue desc/eid vectors for tile t+4 */                   \
    XTR16(dq0, sdN);                                                           \
    dq0 = dq1; dq1 = descb[(t_ + 4) * 16 + l16];                               \
    eq0 = eq1; eq1 = eidb [(t_ + 4) * 16 + l16];                               \
    /* A fragments: read own edge's f32 row, scale by C, pack f16 */           \
    const float* ab_ = &AstW[cc * ASTP];                                       \
    float4 f0_ = *(const float4*)&ab_[g * 8];                                  \
    float4 f1_ = *(const float4*)&ab_[g * 8 + 4];                              \
    uint4 A0u_ = make_uint4(pkh(vC * f0_.x, vC * f0_.y), pkh(vC * f0_.z, vC * f0_.w), \
                            pkh(vC * f1_.x, vC * f1_.y), pkh(vC * f1_.z, vC * f1_.w)); \
    uint4 A1u_;                                                                \
    if (g < 2) {                                                               \
        float4 h0_ = *(const float4*)&ab_[32 + g * 8];                         \
        float4 h1_ = *(const float4*)&ab_[36 + g * 8];                         \
        A1u_ = make_uint4(pkh(vC * h0_.x, vC * h0_.y), pkh(vC * h0_.z, vC * h0_.w), \
                          pkh(vC * h1_.x, vC * h1_.y), pkh(vC * h1_.z, vC * h1_.w)); \
    } else if (g == 2) {                                                       \
        float2 hv_ = *(const float2*)&ab_[48];                                 \
        A1u_ = make_uint4(pkh(vC * hv_.x, vC * hv_.y), pkh(vC, 0.f), 0u, 0u);  \
    } else {                                                                   \
        A1u_ = make_uint4(0u, 0u, 0u, 0u);                                     \
    }                                                                          \
    half8_t A0_ = __builtin_bit_cast(half8_t, A0u_);                           \
    half8_t A1_ = __builtin_bit_cast(half8_t, A1u_);                           \
    f32x4_t acc_[8];                                                           \
    _Pragma("unroll")                                                          \
    for (int nt = 0; nt < 8; ++nt) {                                           \
        uint4 b0_ = *(const uint4*)&Blds[(nt * 16 + cc) * BPITCH + 4 * g];     \
        uint4 b1_ = *(const uint4*)&Blds[(nt * 16 + cc) * BPITCH + 16 + 4 * g];\
        f32x4_t a_ = (f32x4_t){0.f, 0.f, 0.f, 0.f};                            \
        a_ = __builtin_amdgcn_mfma_f32_16x16x32_f16(A0_, __builtin_bit_cast(half8_t, b0_), a_, 0, 0, 0); \
        a_ = __builtin_amdgcn_mfma_f32_16x16x32_f16(A1_, __builtin_bit_cast(half8_t, b1_), a_, 0, 0, 0); \
        acc_[nt] = a_;                                                         \
    }                                                                          \
    /* W transpose into same region (Ast dead now): f16 pairs (h, h+64) */     \
    _Pragma("unroll")                                                          \
    for (int m = 0; m < 4; ++m)                                                \
        _Pragma("unroll")                                                      \
        for (int r = 0; r < 4; ++r)                                            \
            Ww[(g * 4 + r) * WPITCH + m * 16 + cc] = pkh(acc_[m][r], acc_[m + 4][r]); \
    unsigned int wv_[16];                                                      \
    _Pragma("unroll")                                                          \
    for (int e2 = 0; e2 < 16; ++e2)                                            \
        wv_[e2] = Ww[e2 * WPITCH + lane];                                      \
    /* register run-merge (evpC preloaded one tile earlier) */                 \
    _Pragma("unroll")                                                          \
    for (int e2 = 0; e2 < 16; ++e2) {                                          \
        int src_ = sd0[e2] & 0xFFFFF;                                          \
        if (src_ != cur) {                                                     \
            if (cur >= 0) {                                                    \
                float* dst_ = agg + (size_t)cur * HIDDEN + lane;               \
                if (runc) { dst_[0] = r0; dst_[64] = r1; }                     \
                else { unsafeAtomicAdd(dst_, r0); unsafeAtomicAdd(dst_ + 64, r1); } \
                runc = true;                                                   \
            }                                                                  \
            cur = src_; r0 = 0.f; r1 = 0.f;                                    \
        }                                                                      \
        r0 = fmaf(cvlo(wv_[e2]), cvlo(evpC[e2]), r0);                          \
        r1 = fmaf(cvhi(wv_[e2]), cvhi(evpC[e2]), r1);                          \
    }                                                                          \
    /* issue evp for tile t+1 (descs sd1 already extracted) */                 \
    _Pragma("unroll")                                                          \
    for (int j = 0; j < 16; ++j)                                               \
        evpC[j] = embp[(((unsigned int)sd1[j]) >> 20) * 64 + lane];            \
    /* rotate descriptor scalars */                                            \
    _Pragma("unroll")                                                          \
    for (int j = 0; j < 16; ++j) { sd0[j] = sd1[j]; sd1[j] = sdN[j]; }         \
}

    for (int t = 0; t < 8; t += 2) {
        GBODY(vrA, vCA_, t);
        GBODY(vrB, vCB_, t + 1);
    }
#undef GBODY
#undef XTR16

    // final flush
    if (cur >= 0) {
        int nxt = desc[wbeg + 128] & 0xFFFFF;
        float* dst = agg + (size_t)cur * HIDDEN + lane;
        if (runc && nxt != cur) {
            dst[0]  = r0;
            dst[64] = r1;
        } else {
            unsafeAtomicAdd(dst,      r0);
            unsafeAtomicAdd(dst + 64, r1);
        }
    }
}

// ======================= tier-2 gather: VALU streaming =======================
__global__ __launch_bounds__(256) void gather_stream(
    const int* __restrict__ rowptr, const int* __restrict__ desc,
    const float* __restrict__ cC, const int* __restrict__ eidA,
    const float* __restrict__ ea, const float* __restrict__ emb,
    const float* __restrict__ dpw, const float* __restrict__ dpb,
    float* __restrict__ agg, int N, int nwaves)
{
    __shared__ unsigned int sh_ea[4][4][32];
    int lane  = threadIdx.x & 63;
    int wslot = threadIdx.x >> 6;
    int wid = __builtin_amdgcn_readfirstlane((int)((blockIdx.x * blockDim.x + threadIdx.x) >> 6));

    hf2 whA[25], whB[25];
    {
        const float* wr0 = dpw + (size_t)(2 * lane) * NRBF;
        const float* wr1 = wr0 + NRBF;
#pragma unroll
        for (int q = 0; q < 25; ++q) {
            float2 x = *(const float2*)(wr0 + 2 * q);
            float2 y = *(const float2*)(wr1 + 2 * q);
            whA[q] = __builtin_bit_cast(hf2, pkh(x.x, x.y));
            whB[q] = __builtin_bit_cast(hf2, pkh(y.x, y.y));
        }
    }
    float2 db = *(const float2*)(dpb + 2 * lane);

    int M  = rowptr[N];
    int CH = (M + nwaves - 1) / nwaves;
    int c0 = min(wid * CH, M);
    int c1 = min(c0 + CH, M);

    int   cur = -1, run_start = c0;
    float a0 = 0.f, a1 = 0.f;

    for (int i = c0; i < c1; i += 4) {
        int sv[4]; float cf[4]; int ed[4]; float2 ev[4]; float2 eaf[4];
#pragma unroll
        for (int j = 0; j < 4; ++j)
            if (i + j < c1) { sv[j] = desc[i + j]; cf[j] = cC[i + j]; ed[j] = eidA[i + j]; }
#pragma unroll
        for (int j = 0; j < 4; ++j)
            if (i + j < c1) ev[j] = *(const float2*)(emb + (size_t)((unsigned int)sv[j] >> 20) * HIDDEN + 2 * lane);
#pragma unroll
        for (int j = 0; j < 4; ++j)
            if (i + j < c1 && lane < 25) eaf[j] = *(const float2*)(ea + (size_t)ed[j] * NRBF + 2 * lane);
#pragma unroll
        for (int j = 0; j < 4; ++j)
            if (i + j < c1 && lane < 28) {
                unsigned int u = 0u;
                if (lane < 25) u = pkh(eaf[j].x, eaf[j].y);
                sh_ea[wslot][j][lane] = u;
            }
#pragma unroll
        for (int j = 0; j < 4; ++j) {
            if (i + j >= c1) break;
            int src = sv[j] & 0xFFFFF;
            if (src != cur) {
                if (cur >= 0) {
                    int rp0 = rowptr[cur], rp1 = rowptr[cur + 1];
                    float* dst = agg + (size_t)cur * HIDDEN + 2 * lane;
                    if (run_start == rp0 && (i + j) == rp1) {
                        *(float2*)dst = make_float2(a0, a1);
                    } else {
                        unsafeAtomicAdd(dst, a0);
                        unsafeAtomicAdd(dst + 1, a1);
                    }
                }
                cur = src; run_start = i + j; a0 = 0.f; a1 = 0.f;
            }
            float s0 = 0.f, s1 = 0.f;
#pragma unroll
            for (int qq = 0; qq < 6; ++qq) {
                uint4 u = *(const uint4*)&sh_ea[wslot][j][qq * 4];
#pragma unroll
                for (int t = 0; t < 4; ++t) {
                    unsigned int ww = (t == 0) ? u.x : (t == 1) ? u.y : (t == 2) ? u.z : u.w;
                    hf2 e2 = __builtin_bit_cast(hf2, ww);
                    s0 = fmaf((float)e2[0], (float)whA[qq*4+t][0], fmaf((float)e2[1], (float)whA[qq*4+t][1], s0));
                    s1 = fmaf((float)e2[0], (float)whB[qq*4+t][0], fmaf((float)e2[1], (float)whB[qq*4+t][1], s1));
                }
            }
            {
                hf2 e2 = __builtin_bit_cast(hf2, sh_ea[wslot][j][24]);
                s0 = fmaf((float)e2[0], (float)whA[24][0], fmaf((float)e2[1], (float)whA[24][1], s0));
                s1 = fmaf((float)e2[0], (float)whB[24][0], fmaf((float)e2[1], (float)whB[24][1], s1));
            }
            float W0 = (s0 + db.x) * cf[j];
            float W1 = (s1 + db.y) * cf[j];
            a0 = fmaf(W0, ev[j].x, a0);
            a1 = fmaf(W1, ev[j].y, a1);
        }
    }
    if (cur >= 0) {
        int rp0 = rowptr[cur], rp1 = rowptr[cur + 1];
        float* dst = agg + (size_t)cur * HIDDEN + 2 * lane;
        if (run_start == rp0 && c1 == rp1) {
            *(float2*)dst = make_float2(a0, a1);
        } else {
            unsafeAtomicAdd(dst, a0);
            unsafeAtomicAdd(dst + 1, a1);
        }
    }
}

// ======================= tier-3 fallback =======================
__global__ __launch_bounds__(256) void edge_kernel(
    const int* __restrict__ z, const int* __restrict__ ei,
    const float* __restrict__ ew, const float* __restrict__ ea,
    const float* __restrict__ emb, const float* __restrict__ dpw,
    const float* __restrict__ dpb, float* __restrict__ agg, int E)
{
    int e = blockIdx.x * 256 + threadIdx.x;
    if (e >= E) return;
    float r = ew[e];
    if (!(r < CUTOFF_F)) return;
    float C = 0.5f * (cosf(r * PI_OVER_CUTOFF) + 1.0f);
    int src = ei[e];
    int dst = ei[E + e];
    int zt  = z[dst];
    float av[NRBF];
#pragma unroll
    for (int k = 0; k < NRBF; ++k) av[k] = ea[(size_t)e * NRBF + k];
    const float* er = emb + (size_t)zt * HIDDEN;
    float*       ar = agg + (size_t)src * HIDDEN;
#pragma unroll 2
    for (int h = 0; h < HIDDEN; ++h) {
        const float* wrow = dpw + h * NRBF;
        float s0 = 0.f, s1 = 0.f;
#pragma unroll
        for (int k = 0; k < NRBF; k += 2) {
            s0 = fmaf(av[k],     wrow[k],     s0);
            s1 = fmaf(av[k + 1], wrow[k + 1], s1);
        }
        float w2 = (dpb[h] + s0 + s1) * C;
        unsafeAtomicAdd(&ar[h], w2 * er[h]);
    }
}

// ======================= Combine: bf16 MFMA GEMM =======================
__global__ __launch_bounds__(256) void combine_mfma(
    const float* __restrict__ nf, const float* __restrict__ cw,
    const float* __restrict__ cbias, float* out, int N)
{
    __shared__ unsigned int As_u[64 * 20];
    __shared__ unsigned int Bs_u[128 * 20];
    int tid  = threadIdx.x;
    int w    = tid >> 6;
    int lane = tid & 63;
    int c    = lane & 15;
    int g    = lane >> 4;
    int row0 = blockIdx.x * 64;

    f32x4_t acc[8];
#pragma unroll
    for (int q = 0; q < 8; ++q) acc[q] = (f32x4_t){0.f, 0.f, 0.f, 0.f};

    for (int ks = 0; ks < 8; ++ks) {
        const float* src = (ks < 4) ? nf : out;
        int kb = (ks & 3) * 32;
        {
            int r = tid >> 2, kq = tid & 3;
            int row = row0 + r;
            float4 v0 = make_float4(0.f, 0.f, 0.f, 0.f), v1 = v0;
            if (row < N) {
                const float4* p = (const float4*)(src + (size_t)row * HIDDEN + kb + kq * 8);
                v0 = p[0]; v1 = p[1];
            }
            *(uint4*)&As_u[r * 20 + kq * 4] =
                make_uint4(pk_bf16(v0.x, v0.y), pk_bf16(v0.z, v0.w),
                           pk_bf16(v1.x, v1.y), pk_bf16(v1.z, v1.w));
        }
        {
            int j = tid >> 1, hf = tid & 1;
            const float4* p = (const float4*)(cw + (size_t)j * 256 + ks * 32 + hf * 16);
            float4 b0 = p[0], b1 = p[1], b2 = p[2], b3 = p[3];
            *(uint4*)&Bs_u[j * 20 + hf * 8] =
                make_uint4(pk_bf16(b0.x, b0.y), pk_bf16(b0.z, b0.w),
                           pk_bf16(b1.x, b1.y), pk_bf16(b1.z, b1.w));
            *(uint4*)&Bs_u[j * 20 + hf * 8 + 4] =
                make_uint4(pk_bf16(b2.x, b2.y), pk_bf16(b2.z, b2.w),
                           pk_bf16(b3.x, b3.y), pk_bf16(b3.z, b3.w));
        }
        __syncthreads();
        uint4 au = *(const uint4*)&As_u[(w * 16 + c) * 20 + g * 4];
        short8_t af = __builtin_bit_cast(short8_t, au);
#pragma unroll
        for (int cbk = 0; cbk < 8; ++cbk) {
            uint4 bu = *(const uint4*)&Bs_u[(cbk * 16 + c) * 20 + g * 4];
            short8_t bf = __builtin_bit_cast(short8_t, bu);
            acc[cbk] = __builtin_amdgcn_mfma_f32_16x16x32_bf16(af, bf, acc[cbk], 0, 0, 0);
        }
        __syncthreads();
    }
#pragma unroll
    for (int cbk = 0; cbk < 8; ++cbk) {
        float bias = cbias[cbk * 16 + c];
#pragma unroll
        for (int r = 0; r < 4; ++r) {
            int row = row0 + w * 16 + g * 4 + r;
            if (row < N) out[(size_t)row * HIDDEN + cbk * 16 + c] = acc[cbk][r] + bias;
        }
    }
}

// ======================= launch =======================

extern "C" void kernel_launch(void* const* d_in, const int* in_sizes, int n_in,
                              void* d_out, int out_size, void* d_ws, size_t ws_size,
                              hipStream_t stream)
{
    const int*   z   = (const int*)  d_in[0];
    const float* nf  = (const float*)d_in[1];
    const int*   ei  = (const int*)  d_in[2];
    const float* ew  = (const float*)d_in[3];
    const float* ea  = (const float*)d_in[4];
    const float* emb = (const float*)d_in[5];
    const float* dpw = (const float*)d_in[6];
    const float* dpb = (const float*)d_in[7];
    const float* cw  = (const float*)d_in[8];
    const float* cb  = (const float*)d_in[9];
    float* out = (float*)d_out;

    int N = in_sizes[0];
    int E = in_sizes[3];
    int NT = in_sizes[5] / HIDDEN;   // emb rows (95)

    size_t hdr  = ((size_t)2 * N + 1 + 1024 + 3) & ~(size_t)3;   // u32s
    size_t Epad = (size_t)E + 512;
    size_t need1 = (hdr + 3 * Epad + (size_t)NT * 64 + 16) * 4;
    size_t need2 = (hdr + (size_t)3 * E) * 4;

    (void)hipMemsetAsync(out, 0, (size_t)N * HIDDEN * sizeof(float), stream);

    int nb1 = (N + 1023) / 1024;

    if (ws_size >= need1) {
        int* rowptr = (int*)d_ws;
        int* woff   = rowptr + (N + 1);
        int* bsum   = woff + N;
        int* desc   = (int*)d_ws + hdr;
        int* eidA   = desc + Epad;
        float* CAa  = (float*)(eidA + Epad);
        unsigned int* embp = (unsigned int*)(CAa + Epad);

        (void)hipMemsetAsync(woff, 0, (size_t)N * 4, stream);
        hist_kernel<<<(E + 255) / 256, 256, 0, stream>>>(ei, ew, woff, E);
        scan1_kernel<<<nb1, 256, 0, stream>>>(woff, rowptr, bsum, N);
        scan2_kernel<<<1, 256, 0, stream>>>(bsum, rowptr, nb1, N);
        scan3_kernel<<<nb1, 256, 0, stream>>>(rowptr, woff, bsum, N);
        scatter_slim<<<(E + 255) / 256, 256, 0, stream>>>(z, ei, ew, woff,
                                                          desc, eidA, CAa, E);
        pad_pack_kernel<<<(NT * 64 + 255) / 256, 256, 0, stream>>>(
            rowptr, N, desc, eidA, CAa, emb, embp, NT);
        int nblk = (E + EPB - 1) / EPB;
        gather_mfma<<<nblk, 256, 0, stream>>>(rowptr, desc, eidA, CAa, ea,
                                              embp, dpw, dpb, out, N);
    } else if (ws_size >= need2) {
        int* rowptr = (int*)d_ws;
        int* woff   = rowptr + (N + 1);
        int* bsum   = woff + N;
        int* desc   = (int*)d_ws + hdr;
        float* cCA  = (float*)(desc + E);
        int* eidA   = (int*)(cCA + E);

        (void)hipMemsetAsync(woff, 0, (size_t)N * 4, stream);
        hist_kernel<<<(E + 255) / 256, 256, 0, stream>>>(ei, ew, woff, E);
        scan1_kernel<<<nb1, 256, 0, stream>>>(woff, rowptr, bsum, N);
        scan2_kernel<<<1, 256, 0, stream>>>(bsum, rowptr, nb1, N);
        scan3_kernel<<<nb1, 256, 0, stream>>>(rowptr, woff, bsum, N);
        scatter_slim<<<(E + 255) / 256, 256, 0, stream>>>(z, ei, ew, woff,
                                                          desc, eidA, cCA, E);
        const int blocks = 2048;
        gather_stream<<<blocks, 256, 0, stream>>>(rowptr, desc, cCA, eidA,
                                                  ea, emb, dpw, dpb, out, N,
                                                  blocks * 4);
    } else {
        edge_kernel<<<(E + 255) / 256, 256, 0, stream>>>(z, ei, ew, ea, emb,
                                                         dpw, dpb, out, E);
    }

    combine_mfma<<<(N + 63) / 64, 256, 0, stream>>>(nf, cw, cb, out, N);
}